// Round 1
// baseline (344.502 us; speedup 1.0000x reference)
//
#include <hip/hip_runtime.h>
#include <stddef.h>

#define CIN  128
#define COUT 128
#define KK   27
#define TM   64

// ---------------------------------------------------------------------------
// Phase 1: compact per-offset lists of (n_out, src) pairs for k != 13.
// Density ~2.4% for off-center offsets -> ~1200 entries each.
// ---------------------------------------------------------------------------
__global__ void build_lists(const int* __restrict__ nbr, int N,
                            int2* __restrict__ pairs, int* __restrict__ counts) {
    int k = blockIdx.y;
    if (k == 13) return;                       // center handled densely
    int n = blockIdx.x * blockDim.x + threadIdx.x;
    if (n >= N) return;
    int src = nbr[k * N + n];
    if (src >= 0) {
        int pos = atomicAdd(&counts[k], 1);    // compiler wave-aggregates
        pairs[(size_t)k * N + pos] = make_int2(n, src);
    }
}

// ---------------------------------------------------------------------------
// Tiled gather-GEMM: 64 gathered rows x 128 cols, K=128, fp32 VALU.
// 256 threads, each computes a 4x8 register micro-tile.
// CENTER=true: k=13, src from nbr (== n), plain stores (initializes out).
// CENTER=false: rows from compacted list, atomicAdd accumulate.
// ---------------------------------------------------------------------------
template<bool CENTER>
__global__ __launch_bounds__(256) void spconv_gemm(
    const float* __restrict__ feats,
    const float* __restrict__ Wbase,
    const int*   __restrict__ nbr,
    const int2*  __restrict__ pairs,
    const int*   __restrict__ counts,
    float* __restrict__ out, int N)
{
    int k, cnt;
    if (CENTER) { k = 13; cnt = N; }
    else {
        k = blockIdx.y;
        if (k == 13) return;
        cnt = counts[k];
    }
    const int tile0 = blockIdx.x * TM;
    if (tile0 >= cnt) return;

    const float* Wk = Wbase + (size_t)k * CIN * COUT;

    __shared__ float Alds[TM][CIN + 4];    // +4 pad: row-vs-row reads 2-way max
    __shared__ float Wlds[32][COUT + 4];
    __shared__ int   n_of[TM];

    // ---- stage A tile: 64 rows x 128 floats (gathered), float4 loads ----
    #pragma unroll
    for (int j = 0; j < 8; ++j) {
        int f   = threadIdx.x + 256 * j;   // 0..2047 float4 slots
        int row = f >> 5;
        int c4  = f & 31;
        int r   = tile0 + row;
        float4 v = make_float4(0.f, 0.f, 0.f, 0.f);
        int n_out = -1;
        if (r < cnt) {
            int src;
            if (CENTER) { n_out = r; src = nbr[13 * N + r]; }
            else        { int2 p = pairs[(size_t)k * N + r]; n_out = p.x; src = p.y; }
            if (src >= 0)
                v = *reinterpret_cast<const float4*>(feats + (size_t)src * CIN + c4 * 4);
        }
        *reinterpret_cast<float4*>(&Alds[row][c4 * 4]) = v;
        if (c4 == 0) n_of[row] = n_out;
    }

    float acc[4][8];
    #pragma unroll
    for (int i = 0; i < 4; ++i)
        #pragma unroll
        for (int j = 0; j < 8; ++j) acc[i][j] = 0.f;

    const int tcol = threadIdx.x & 15;     // cols tcol*8 .. +7
    const int trow = threadIdx.x >> 4;     // rows trow*4 .. +3

    // ---- K loop in 4 chunks of 32, W chunk staged in LDS ----
    for (int kc = 0; kc < 4; ++kc) {
        __syncthreads();                   // A-stage done (kc=0) / Wlds reuse
        #pragma unroll
        for (int j = 0; j < 4; ++j) {
            int f   = threadIdx.x + 256 * j;  // 0..1023
            int row = f >> 5;
            int c4  = f & 31;
            float4 v = *reinterpret_cast<const float4*>(
                Wk + (size_t)(kc * 32 + row) * COUT + c4 * 4);
            *reinterpret_cast<float4*>(&Wlds[row][c4 * 4]) = v;
        }
        __syncthreads();

        #pragma unroll
        for (int kk = 0; kk < 32; ++kk) {
            float a_[4];
            #pragma unroll
            for (int i = 0; i < 4; ++i)
                a_[i] = Alds[trow * 4 + i][kc * 32 + kk];
            float4 b0 = *reinterpret_cast<const float4*>(&Wlds[kk][tcol * 8]);
            float4 b1 = *reinterpret_cast<const float4*>(&Wlds[kk][tcol * 8 + 4]);
            float b_[8] = {b0.x, b0.y, b0.z, b0.w, b1.x, b1.y, b1.z, b1.w};
            #pragma unroll
            for (int i = 0; i < 4; ++i)
                #pragma unroll
                for (int j = 0; j < 8; ++j)
                    acc[i][j] = fmaf(a_[i], b_[j], acc[i][j]);
        }
    }

    // ---- store ----
    #pragma unroll
    for (int i = 0; i < 4; ++i) {
        int row = trow * 4 + i;
        int n = n_of[row];
        if (n < 0) continue;
        float* dst = out + (size_t)n * COUT + tcol * 8;
        if (CENTER) {
            *reinterpret_cast<float4*>(dst) =
                make_float4(acc[i][0], acc[i][1], acc[i][2], acc[i][3]);
            *reinterpret_cast<float4*>(dst + 4) =
                make_float4(acc[i][4], acc[i][5], acc[i][6], acc[i][7]);
        } else {
            #pragma unroll
            for (int j = 0; j < 8; ++j) atomicAdd(dst + j, acc[i][j]);
        }
    }
}

// ---------------------------------------------------------------------------
// Fallback (ws too small): one block per voxel, uniform-branch k loop.
// ---------------------------------------------------------------------------
__global__ __launch_bounds__(128) void naive_spconv(
    const float* __restrict__ feats, const float* __restrict__ Wbase,
    const int* __restrict__ nbr, float* __restrict__ out, int N)
{
    int n  = blockIdx.x;
    int co = threadIdx.x;
    __shared__ float frow[CIN];
    float acc = 0.f;
    for (int k = 0; k < KK; ++k) {
        int src = nbr[k * N + n];          // uniform across block
        if (src < 0) continue;
        __syncthreads();
        frow[co] = feats[(size_t)src * CIN + co];
        __syncthreads();
        const float* Wk = Wbase + (size_t)k * CIN * COUT;
        #pragma unroll 8
        for (int ci = 0; ci < CIN; ++ci)
            acc = fmaf(frow[ci], Wk[ci * COUT + co], acc);
    }
    out[(size_t)n * COUT + co] = acc;
}

extern "C" void kernel_launch(void* const* d_in, const int* in_sizes, int n_in,
                              void* d_out, int out_size, void* d_ws, size_t ws_size,
                              hipStream_t stream) {
    const float* feats = (const float*)d_in[0];
    const float* Wb    = (const float*)d_in[1];
    const int*   nbr   = (const int*)d_in[2];
    float* out = (float*)d_out;
    const int N = in_sizes[0] / CIN;

    size_t need = 128 + (size_t)KK * N * sizeof(int2);
    if (ws_size >= need) {
        int*  counts = (int*)d_ws;
        int2* pairs  = (int2*)((char*)d_ws + 128);
        hipMemsetAsync(counts, 0, 128, stream);

        dim3 bgrid((N + 255) / 256, KK);
        build_lists<<<bgrid, 256, 0, stream>>>(nbr, N, pairs, counts);

        dim3 cgrid((N + TM - 1) / TM, 1);
        spconv_gemm<true><<<cgrid, 256, 0, stream>>>(feats, Wb, nbr, nullptr, nullptr, out, N);

        dim3 sgrid((N + TM - 1) / TM, KK);
        spconv_gemm<false><<<sgrid, 256, 0, stream>>>(feats, Wb, nullptr, pairs, counts, out, N);
    } else {
        naive_spconv<<<N, 128, 0, stream>>>(feats, Wb, nbr, out, N);
    }
}

// Round 2
// 182.557 us; speedup vs baseline: 1.8871x; 1.8871x over previous
//
#include <hip/hip_runtime.h>
#include <stddef.h>

#define CIN  128
#define COUT 128
#define KK   27
#define TM   64

// ============================================================================
// Phase 1 (no atomics): count valid entries per (k, block) via ballot.
// k==13 (center) handled densely elsewhere -> counted as 0 here.
// ============================================================================
__global__ __launch_bounds__(256) void count_valid(
    const int* __restrict__ nbr, int N, int nblk, int* __restrict__ blk_cnt)
{
    int k = blockIdx.y;
    int n = blockIdx.x * 256 + threadIdx.x;
    bool valid = (k != 13) && (n < N) && (nbr[(size_t)k * N + n] >= 0);
    unsigned long long m = __ballot(valid);
    __shared__ int wcnt[4];
    int wave = threadIdx.x >> 6;
    if ((threadIdx.x & 63) == 0) wcnt[wave] = __popcll(m);
    __syncthreads();
    if (threadIdx.x == 0)
        blk_cnt[(size_t)k * nblk + blockIdx.x] = wcnt[0] + wcnt[1] + wcnt[2] + wcnt[3];
}

// ============================================================================
// Phase 2: per-k exclusive scan of block counts (nblk <= 256); totals -> counts.
// ============================================================================
__global__ __launch_bounds__(256) void scan_blocks(
    int* __restrict__ blk_cnt, int nblk, int* __restrict__ counts)
{
    int k = blockIdx.x;
    int tid = threadIdx.x;
    __shared__ int buf[256];
    int v = (tid < nblk) ? blk_cnt[(size_t)k * nblk + tid] : 0;
    buf[tid] = v;
    __syncthreads();
    for (int off = 1; off < 256; off <<= 1) {
        int t = (tid >= off) ? buf[tid - off] : 0;
        __syncthreads();
        buf[tid] += t;
        __syncthreads();
    }
    if (tid < nblk) blk_cnt[(size_t)k * nblk + tid] = buf[tid] - v;  // exclusive
    if (tid == 255) counts[k] = buf[255];
}

// ============================================================================
// Phase 3: tile bases (exclusive scan of ceil(counts[k]/TM)) -- 27 values.
// ============================================================================
__global__ void tile_bases(const int* __restrict__ counts, int* __restrict__ tbase)
{
    if (threadIdx.x == 0) {
        int acc = 0;
        for (int k = 0; k < KK; ++k) { tbase[k] = acc; acc += (counts[k] + TM - 1) / TM; }
        tbase[KK] = acc;
    }
}

// ============================================================================
// Phase 4: scatter (n_out, src) pairs using ballot-prefix, no atomics.
// ============================================================================
__global__ __launch_bounds__(256) void scatter_pairs(
    const int* __restrict__ nbr, int N, int nblk,
    const int* __restrict__ blk_cnt, int2* __restrict__ pairs)
{
    int k = blockIdx.y;
    if (k == 13) return;
    int n = blockIdx.x * 256 + threadIdx.x;
    int src = -1;
    if (n < N) src = nbr[(size_t)k * N + n];
    bool valid = (src >= 0);
    unsigned long long m = __ballot(valid);
    __shared__ int wcnt[4];
    int wave = threadIdx.x >> 6;
    int lane = threadIdx.x & 63;
    if (lane == 0) wcnt[wave] = __popcll(m);
    __syncthreads();
    int base = blk_cnt[(size_t)k * nblk + blockIdx.x];
    for (int w = 0; w < wave; ++w) base += wcnt[w];
    int pfx = __popcll(m & ((1ull << lane) - 1ull));
    if (valid) pairs[(size_t)k * N + base + pfx] = make_int2(n, src);
}

// ============================================================================
// Center GEMM (k=13, dense, always valid): initializes all of d_out.
// 256 threads, 64x128 tile, K=128, fp32 VALU, 4x8 register micro-tile.
// ============================================================================
__global__ __launch_bounds__(256) void spconv_center(
    const float* __restrict__ feats, const float* __restrict__ Wbase,
    const int* __restrict__ nbr, float* __restrict__ out, int N)
{
    const int tile0 = blockIdx.x * TM;
    const float* Wk = Wbase + (size_t)13 * CIN * COUT;

    __shared__ float Alds[TM][CIN + 4];
    __shared__ float Wlds[32][COUT + 4];

    #pragma unroll
    for (int j = 0; j < 8; ++j) {
        int f   = threadIdx.x + 256 * j;
        int row = f >> 5;
        int c4  = f & 31;
        int r   = tile0 + row;
        float4 v = make_float4(0.f, 0.f, 0.f, 0.f);
        if (r < N) {
            int src = nbr[(size_t)13 * N + r];
            if (src >= 0)
                v = *reinterpret_cast<const float4*>(feats + (size_t)src * CIN + c4 * 4);
        }
        *reinterpret_cast<float4*>(&Alds[row][c4 * 4]) = v;
    }

    float acc[4][8];
    #pragma unroll
    for (int i = 0; i < 4; ++i)
        #pragma unroll
        for (int j = 0; j < 8; ++j) acc[i][j] = 0.f;

    const int tcol = threadIdx.x & 15;
    const int trow = threadIdx.x >> 4;

    for (int kc = 0; kc < 4; ++kc) {
        __syncthreads();
        #pragma unroll
        for (int j = 0; j < 4; ++j) {
            int f   = threadIdx.x + 256 * j;
            int row = f >> 5;
            int c4  = f & 31;
            float4 v = *reinterpret_cast<const float4*>(
                Wk + (size_t)(kc * 32 + row) * COUT + c4 * 4);
            *reinterpret_cast<float4*>(&Wlds[row][c4 * 4]) = v;
        }
        __syncthreads();

        #pragma unroll
        for (int kk = 0; kk < 32; ++kk) {
            float a_[4];
            #pragma unroll
            for (int i = 0; i < 4; ++i)
                a_[i] = Alds[trow * 4 + i][kc * 32 + kk];
            float4 b0 = *reinterpret_cast<const float4*>(&Wlds[kk][tcol * 8]);
            float4 b1 = *reinterpret_cast<const float4*>(&Wlds[kk][tcol * 8 + 4]);
            float b_[8] = {b0.x, b0.y, b0.z, b0.w, b1.x, b1.y, b1.z, b1.w};
            #pragma unroll
            for (int i = 0; i < 4; ++i)
                #pragma unroll
                for (int j = 0; j < 8; ++j)
                    acc[i][j] = fmaf(a_[i], b_[j], acc[i][j]);
        }
    }

    #pragma unroll
    for (int i = 0; i < 4; ++i) {
        int r = tile0 + trow * 4 + i;
        if (r >= N) continue;
        float* dst = out + (size_t)r * COUT + tcol * 8;
        *reinterpret_cast<float4*>(dst)     = make_float4(acc[i][0], acc[i][1], acc[i][2], acc[i][3]);
        *reinterpret_cast<float4*>(dst + 4) = make_float4(acc[i][4], acc[i][5], acc[i][6], acc[i][7]);
    }
}

// ============================================================================
// Sparse GEMM: persistent blocks walk device-computed tile list; atomicAdd out.
// ============================================================================
__global__ __launch_bounds__(256) void spconv_sparse(
    const float* __restrict__ feats, const float* __restrict__ Wbase,
    const int2* __restrict__ pairs, const int* __restrict__ counts,
    const int* __restrict__ tbase, float* __restrict__ out, int N)
{
    __shared__ float Alds[TM][CIN + 4];
    __shared__ float Wlds[32][COUT + 4];
    __shared__ int   n_of[TM];
    __shared__ int   sk, stile0, scnt;

    const int total = tbase[KK];
    const int tcol = threadIdx.x & 15;
    const int trow = threadIdx.x >> 4;

    for (int t = blockIdx.x; t < total; t += gridDim.x) {
        if (threadIdx.x == 0) {
            int k = 0;
            while (!(t >= tbase[k] && t < tbase[k + 1])) ++k;
            sk = k;
            stile0 = (t - tbase[k]) * TM;
            scnt = counts[k];
        }
        __syncthreads();
        const int k = sk, tile0 = stile0, cnt = scnt;
        const float* Wk = Wbase + (size_t)k * CIN * COUT;

        #pragma unroll
        for (int j = 0; j < 8; ++j) {
            int f   = threadIdx.x + 256 * j;
            int row = f >> 5;
            int c4  = f & 31;
            int r   = tile0 + row;
            float4 v = make_float4(0.f, 0.f, 0.f, 0.f);
            int n_out = -1;
            if (r < cnt) {
                int2 p = pairs[(size_t)k * N + r];
                n_out = p.x;
                v = *reinterpret_cast<const float4*>(feats + (size_t)p.y * CIN + c4 * 4);
            }
            *reinterpret_cast<float4*>(&Alds[row][c4 * 4]) = v;
            if (c4 == 0) n_of[row] = n_out;
        }

        float acc[4][8];
        #pragma unroll
        for (int i = 0; i < 4; ++i)
            #pragma unroll
            for (int j = 0; j < 8; ++j) acc[i][j] = 0.f;

        for (int kc = 0; kc < 4; ++kc) {
            __syncthreads();
            #pragma unroll
            for (int j = 0; j < 4; ++j) {
                int f   = threadIdx.x + 256 * j;
                int row = f >> 5;
                int c4  = f & 31;
                float4 v = *reinterpret_cast<const float4*>(
                    Wk + (size_t)(kc * 32 + row) * COUT + c4 * 4);
                *reinterpret_cast<float4*>(&Wlds[row][c4 * 4]) = v;
            }
            __syncthreads();

            #pragma unroll
            for (int kk = 0; kk < 32; ++kk) {
                float a_[4];
                #pragma unroll
                for (int i = 0; i < 4; ++i)
                    a_[i] = Alds[trow * 4 + i][kc * 32 + kk];
                float4 b0 = *reinterpret_cast<const float4*>(&Wlds[kk][tcol * 8]);
                float4 b1 = *reinterpret_cast<const float4*>(&Wlds[kk][tcol * 8 + 4]);
                float b_[8] = {b0.x, b0.y, b0.z, b0.w, b1.x, b1.y, b1.z, b1.w};
                #pragma unroll
                for (int i = 0; i < 4; ++i)
                    #pragma unroll
                    for (int j = 0; j < 8; ++j)
                        acc[i][j] = fmaf(a_[i], b_[j], acc[i][j]);
            }
        }

        #pragma unroll
        for (int i = 0; i < 4; ++i) {
            int row = trow * 4 + i;
            int n = n_of[row];
            if (n < 0) continue;
            float* dst = out + (size_t)n * COUT + tcol * 8;
            #pragma unroll
            for (int j = 0; j < 8; ++j) atomicAdd(dst + j, acc[i][j]);
        }
        __syncthreads();   // protect LDS before next loop iteration
    }
}

// ============================================================================
// Fallback (ws too small): one block per voxel.
// ============================================================================
__global__ __launch_bounds__(128) void naive_spconv(
    const float* __restrict__ feats, const float* __restrict__ Wbase,
    const int* __restrict__ nbr, float* __restrict__ out, int N)
{
    int n  = blockIdx.x;
    int co = threadIdx.x;
    __shared__ float frow[CIN];
    float acc = 0.f;
    for (int k = 0; k < KK; ++k) {
        int src = nbr[(size_t)k * N + n];
        if (src < 0) continue;
        __syncthreads();
        frow[co] = feats[(size_t)src * CIN + co];
        __syncthreads();
        const float* Wk = Wbase + (size_t)k * CIN * COUT;
        #pragma unroll 8
        for (int ci = 0; ci < CIN; ++ci)
            acc = fmaf(frow[ci], Wk[ci * COUT + co], acc);
    }
    out[(size_t)n * COUT + co] = acc;
}

extern "C" void kernel_launch(void* const* d_in, const int* in_sizes, int n_in,
                              void* d_out, int out_size, void* d_ws, size_t ws_size,
                              hipStream_t stream) {
    const float* feats = (const float*)d_in[0];
    const float* Wb    = (const float*)d_in[1];
    const int*   nbr   = (const int*)d_in[2];
    float* out = (float*)d_out;
    const int N = in_sizes[0] / CIN;
    const int nblk = (N + 255) / 256;

    // ws layout: counts[27] @0 (pad 128) | tbase[28] @128 (pad 256)
    //            | blk_cnt[27*nblk] @256 | pairs[27*N] int2 (8-aligned)
    size_t off_counts = 0;
    size_t off_tbase  = 128;
    size_t off_bcnt   = 256;
    size_t off_pairs  = (off_bcnt + (size_t)KK * nblk * 4 + 7) & ~(size_t)7;
    size_t need = off_pairs + (size_t)KK * N * sizeof(int2);

    if (ws_size >= need && nblk <= 256) {
        int*  counts = (int*)((char*)d_ws + off_counts);
        int*  tbase  = (int*)((char*)d_ws + off_tbase);
        int*  bcnt   = (int*)((char*)d_ws + off_bcnt);
        int2* pairs  = (int2*)((char*)d_ws + off_pairs);

        dim3 g1(nblk, KK);
        count_valid<<<g1, 256, 0, stream>>>(nbr, N, nblk, bcnt);
        scan_blocks<<<KK, 256, 0, stream>>>(bcnt, nblk, counts);
        tile_bases<<<1, 64, 0, stream>>>(counts, tbase);
        scatter_pairs<<<g1, 256, 0, stream>>>(nbr, N, nblk, bcnt, pairs);

        spconv_center<<<(N + TM - 1) / TM, 256, 0, stream>>>(feats, Wb, nbr, out, N);
        spconv_sparse<<<512, 256, 0, stream>>>(feats, Wb, pairs, counts, tbase, out, N);
    } else {
        naive_spconv<<<N, 128, 0, stream>>>(feats, Wb, nbr, out, N);
    }
}

// Round 3
// 98.349 us; speedup vs baseline: 3.5028x; 1.8562x over previous
//
#include <hip/hip_runtime.h>
#include <stddef.h>

#define CIN  128
#define COUT 128
#define KK   27
#define TM   64

// ============================================================================
// Phase 1 (no atomics): count valid entries per (k, block) via ballot.
// ============================================================================
__global__ __launch_bounds__(256) void count_valid(
    const int* __restrict__ nbr, int N, int nblk, int* __restrict__ blk_cnt)
{
    int k = blockIdx.y;
    int n = blockIdx.x * 256 + threadIdx.x;
    bool valid = (k != 13) && (n < N) && (nbr[(size_t)k * N + n] >= 0);
    unsigned long long m = __ballot(valid);
    __shared__ int wcnt[4];
    int wave = threadIdx.x >> 6;
    if ((threadIdx.x & 63) == 0) wcnt[wave] = __popcll(m);
    __syncthreads();
    if (threadIdx.x == 0)
        blk_cnt[(size_t)k * nblk + blockIdx.x] = wcnt[0] + wcnt[1] + wcnt[2] + wcnt[3];
}

// ============================================================================
// Phase 2: per-k exclusive scan of block counts (nblk <= 256); totals -> counts.
// ============================================================================
__global__ __launch_bounds__(256) void scan_blocks(
    int* __restrict__ blk_cnt, int nblk, int* __restrict__ counts)
{
    int k = blockIdx.x;
    int tid = threadIdx.x;
    __shared__ int buf[256];
    int v = (tid < nblk) ? blk_cnt[(size_t)k * nblk + tid] : 0;
    buf[tid] = v;
    __syncthreads();
    for (int off = 1; off < 256; off <<= 1) {
        int t = (tid >= off) ? buf[tid - off] : 0;
        __syncthreads();
        buf[tid] += t;
        __syncthreads();
    }
    if (tid < nblk) blk_cnt[(size_t)k * nblk + tid] = buf[tid] - v;  // exclusive
    if (tid == 255) counts[k] = buf[255];
}

// ============================================================================
// Phase 3: tbase[k] = exclusive scan of ceil(counts[k]/TM);
//          kofs[k]  = exclusive scan of counts[k] (global entry offsets).
// ============================================================================
__global__ void tile_bases(const int* __restrict__ counts,
                           int* __restrict__ tbase, int* __restrict__ kofs)
{
    if (threadIdx.x == 0) {
        int tacc = 0, eacc = 0;
        for (int k = 0; k < KK; ++k) {
            tbase[k] = tacc; tacc += (counts[k] + TM - 1) / TM;
            kofs[k]  = eacc; eacc += counts[k];
        }
        tbase[KK] = tacc;
        kofs[KK]  = eacc;
    }
}

// ============================================================================
// Phase 4: scatter (n_out, src) pairs via ballot-prefix; record pos[k*N+n] =
// global entry offset (kofs[k] + within-k index) or -1. No atomics.
// ============================================================================
__global__ __launch_bounds__(256) void scatter_pairs(
    const int* __restrict__ nbr, int N, int nblk,
    const int* __restrict__ blk_cnt, const int* __restrict__ kofs,
    int2* __restrict__ pairs, int* __restrict__ pos)
{
    int k = blockIdx.y;
    int n = blockIdx.x * 256 + threadIdx.x;
    int src = -1;
    if (k != 13 && n < N) src = nbr[(size_t)k * N + n];
    bool valid = (src >= 0);
    unsigned long long m = __ballot(valid);
    __shared__ int wcnt[4];
    int wave = threadIdx.x >> 6;
    int lane = threadIdx.x & 63;
    if (lane == 0) wcnt[wave] = __popcll(m);
    __syncthreads();
    if (n >= N) return;
    int base = blk_cnt[(size_t)k * nblk + blockIdx.x];
    for (int w = 0; w < wave; ++w) base += wcnt[w];
    int pfx = __popcll(m & ((1ull << lane) - 1ull));
    int idx = base + pfx;
    if (valid) pairs[(size_t)k * N + idx] = make_int2(n, src);
    pos[(size_t)k * N + n] = valid ? (kofs[k] + idx) : -1;
}

// ============================================================================
// Center GEMM (k=13, dense): out[n] = feats[n] @ W[13]. Plain stores.
// 256 threads, 64x128 tile, K=128, fp32 VALU, 4x8 register micro-tile.
// ============================================================================
__global__ __launch_bounds__(256) void spconv_center(
    const float* __restrict__ feats, const float* __restrict__ Wbase,
    const int* __restrict__ nbr, float* __restrict__ out, int N)
{
    const int tile0 = blockIdx.x * TM;
    const float* Wk = Wbase + (size_t)13 * CIN * COUT;

    __shared__ float Alds[TM][CIN + 4];
    __shared__ float Wlds[32][COUT + 4];

    #pragma unroll
    for (int j = 0; j < 8; ++j) {
        int f   = threadIdx.x + 256 * j;
        int row = f >> 5;
        int c4  = f & 31;
        int r   = tile0 + row;
        float4 v = make_float4(0.f, 0.f, 0.f, 0.f);
        if (r < N) {
            int src = nbr[(size_t)13 * N + r];
            if (src >= 0)
                v = *reinterpret_cast<const float4*>(feats + (size_t)src * CIN + c4 * 4);
        }
        *reinterpret_cast<float4*>(&Alds[row][c4 * 4]) = v;
    }

    float acc[4][8];
    #pragma unroll
    for (int i = 0; i < 4; ++i)
        #pragma unroll
        for (int j = 0; j < 8; ++j) acc[i][j] = 0.f;

    const int tcol = threadIdx.x & 15;
    const int trow = threadIdx.x >> 4;

    for (int kc = 0; kc < 4; ++kc) {
        __syncthreads();
        #pragma unroll
        for (int j = 0; j < 4; ++j) {
            int f   = threadIdx.x + 256 * j;
            int row = f >> 5;
            int c4  = f & 31;
            float4 v = *reinterpret_cast<const float4*>(
                Wk + (size_t)(kc * 32 + row) * COUT + c4 * 4);
            *reinterpret_cast<float4*>(&Wlds[row][c4 * 4]) = v;
        }
        __syncthreads();

        #pragma unroll
        for (int kk = 0; kk < 32; ++kk) {
            float a_[4];
            #pragma unroll
            for (int i = 0; i < 4; ++i)
                a_[i] = Alds[trow * 4 + i][kc * 32 + kk];
            float4 b0 = *reinterpret_cast<const float4*>(&Wlds[kk][tcol * 8]);
            float4 b1 = *reinterpret_cast<const float4*>(&Wlds[kk][tcol * 8 + 4]);
            float b_[8] = {b0.x, b0.y, b0.z, b0.w, b1.x, b1.y, b1.z, b1.w};
            #pragma unroll
            for (int i = 0; i < 4; ++i)
                #pragma unroll
                for (int j = 0; j < 8; ++j)
                    acc[i][j] = fmaf(a_[i], b_[j], acc[i][j]);
        }
    }

    #pragma unroll
    for (int i = 0; i < 4; ++i) {
        int r = tile0 + trow * 4 + i;
        if (r >= N) continue;
        float* dst = out + (size_t)r * COUT + tcol * 8;
        *reinterpret_cast<float4*>(dst)     = make_float4(acc[i][0], acc[i][1], acc[i][2], acc[i][3]);
        *reinterpret_cast<float4*>(dst + 4) = make_float4(acc[i][4], acc[i][5], acc[i][6], acc[i][7]);
    }
}

// ============================================================================
// Sparse GEMM: persistent blocks walk tile list; write rows to partial[goff]
// (plain stores, collision-free). Rows with goff >= cap fall back to atomics
// (runs after center, before reduce -> stream-ordered, still correct).
// ============================================================================
__global__ __launch_bounds__(256) void spconv_partial(
    const float* __restrict__ feats, const float* __restrict__ Wbase,
    const int2* __restrict__ pairs, const int* __restrict__ counts,
    const int* __restrict__ tbase, const int* __restrict__ kofs,
    float* __restrict__ partial, float* __restrict__ out, int N, int cap)
{
    __shared__ float Alds[TM][CIN + 4];
    __shared__ float Wlds[32][COUT + 4];
    __shared__ int   n_of[TM];
    __shared__ int   sk, stile0, scnt, skofs;

    const int total = tbase[KK];
    const int tcol = threadIdx.x & 15;
    const int trow = threadIdx.x >> 4;

    for (int t = blockIdx.x; t < total; t += gridDim.x) {
        if (threadIdx.x == 0) {
            int k = 0;
            while (!(t >= tbase[k] && t < tbase[k + 1])) ++k;
            sk = k;
            stile0 = (t - tbase[k]) * TM;
            scnt = counts[k];
            skofs = kofs[k];
        }
        __syncthreads();
        const int k = sk, tile0 = stile0, cnt = scnt, kof = skofs;
        const float* Wk = Wbase + (size_t)k * CIN * COUT;

        #pragma unroll
        for (int j = 0; j < 8; ++j) {
            int f   = threadIdx.x + 256 * j;
            int row = f >> 5;
            int c4  = f & 31;
            int r   = tile0 + row;
            float4 v = make_float4(0.f, 0.f, 0.f, 0.f);
            int n_out = -1;
            if (r < cnt) {
                int2 p = pairs[(size_t)k * N + r];
                n_out = p.x;
                v = *reinterpret_cast<const float4*>(feats + (size_t)p.y * CIN + c4 * 4);
            }
            *reinterpret_cast<float4*>(&Alds[row][c4 * 4]) = v;
            if (c4 == 0) n_of[row] = n_out;
        }

        float acc[4][8];
        #pragma unroll
        for (int i = 0; i < 4; ++i)
            #pragma unroll
            for (int j = 0; j < 8; ++j) acc[i][j] = 0.f;

        for (int kc = 0; kc < 4; ++kc) {
            __syncthreads();
            #pragma unroll
            for (int j = 0; j < 4; ++j) {
                int f   = threadIdx.x + 256 * j;
                int row = f >> 5;
                int c4  = f & 31;
                float4 v = *reinterpret_cast<const float4*>(
                    Wk + (size_t)(kc * 32 + row) * COUT + c4 * 4);
                *reinterpret_cast<float4*>(&Wlds[row][c4 * 4]) = v;
            }
            __syncthreads();

            #pragma unroll
            for (int kk = 0; kk < 32; ++kk) {
                float a_[4];
                #pragma unroll
                for (int i = 0; i < 4; ++i)
                    a_[i] = Alds[trow * 4 + i][kc * 32 + kk];
                float4 b0 = *reinterpret_cast<const float4*>(&Wlds[kk][tcol * 8]);
                float4 b1 = *reinterpret_cast<const float4*>(&Wlds[kk][tcol * 8 + 4]);
                float b_[8] = {b0.x, b0.y, b0.z, b0.w, b1.x, b1.y, b1.z, b1.w};
                #pragma unroll
                for (int i = 0; i < 4; ++i)
                    #pragma unroll
                    for (int j = 0; j < 8; ++j)
                        acc[i][j] = fmaf(a_[i], b_[j], acc[i][j]);
            }
        }

        #pragma unroll
        for (int i = 0; i < 4; ++i) {
            int row = trow * 4 + i;
            int r = tile0 + row;
            if (r >= cnt) continue;
            int goff = kof + r;
            if (goff < cap) {
                float* dst = partial + (size_t)goff * COUT + tcol * 8;
                *reinterpret_cast<float4*>(dst)     = make_float4(acc[i][0], acc[i][1], acc[i][2], acc[i][3]);
                *reinterpret_cast<float4*>(dst + 4) = make_float4(acc[i][4], acc[i][5], acc[i][6], acc[i][7]);
            } else {
                float* dst = out + (size_t)n_of[row] * COUT + tcol * 8;
                #pragma unroll
                for (int j = 0; j < 8; ++j) atomicAdd(dst + j, acc[i][j]);
            }
        }
        __syncthreads();   // protect LDS/n_of before next tile
    }
}

// ============================================================================
// Reduce: out[n] += sum over k of partial[pos[k,n]]. 8 rows/block, 32 thr/row.
// Plain RMW (each n owned by one group). Skips rows with no contributions.
// ============================================================================
__global__ __launch_bounds__(256) void reduce_out(
    const float* __restrict__ partial, const int* __restrict__ pos,
    float* __restrict__ out, int N, int cap)
{
    int n0 = blockIdx.x * 8;
    __shared__ int pos_s[8][28];
    int i = threadIdx.x;
    if (i < 8 * KK) {
        int k = i / 8, r = i % 8;
        int n = n0 + r;
        pos_s[r][k] = (n < N) ? pos[(size_t)k * N + n] : -1;
    }
    __syncthreads();

    int row  = threadIdx.x >> 5;
    int lane = threadIdx.x & 31;
    int n = n0 + row;
    if (n >= N) return;

    float4 acc = make_float4(0.f, 0.f, 0.f, 0.f);
    bool any = false;
    #pragma unroll
    for (int k = 0; k < KK; ++k) {
        int g = pos_s[row][k];
        if (g >= 0 && g < cap) {
            any = true;
            float4 v = *reinterpret_cast<const float4*>(partial + (size_t)g * COUT + lane * 4);
            acc.x += v.x; acc.y += v.y; acc.z += v.z; acc.w += v.w;
        }
    }
    if (any) {
        float4* dst = reinterpret_cast<float4*>(out + (size_t)n * COUT + lane * 4);
        float4 o = *dst;
        o.x += acc.x; o.y += acc.y; o.z += acc.z; o.w += acc.w;
        *dst = o;
    }
}

// ============================================================================
// Fallback (ws too small): one block per voxel.
// ============================================================================
__global__ __launch_bounds__(128) void naive_spconv(
    const float* __restrict__ feats, const float* __restrict__ Wbase,
    const int* __restrict__ nbr, float* __restrict__ out, int N)
{
    int n  = blockIdx.x;
    int co = threadIdx.x;
    __shared__ float frow[CIN];
    float acc = 0.f;
    for (int k = 0; k < KK; ++k) {
        int src = nbr[(size_t)k * N + n];
        if (src < 0) continue;
        __syncthreads();
        frow[co] = feats[(size_t)src * CIN + co];
        __syncthreads();
        const float* Wk = Wbase + (size_t)k * CIN * COUT;
        #pragma unroll 8
        for (int ci = 0; ci < CIN; ++ci)
            acc = fmaf(frow[ci], Wk[ci * COUT + co], acc);
    }
    out[(size_t)n * COUT + co] = acc;
}

extern "C" void kernel_launch(void* const* d_in, const int* in_sizes, int n_in,
                              void* d_out, int out_size, void* d_ws, size_t ws_size,
                              hipStream_t stream) {
    const float* feats = (const float*)d_in[0];
    const float* Wb    = (const float*)d_in[1];
    const int*   nbr   = (const int*)d_in[2];
    float* out = (float*)d_out;
    const int N = in_sizes[0] / CIN;
    const int nblk = (N + 255) / 256;

    // ws layout: counts[32] | tbase[32] | kofs[32] | bcnt[27*nblk]
    //            | pairs[27*N] int2 | pos[27*N] int | partial[cap*128] float
    size_t off_counts = 0;
    size_t off_tbase  = 128;
    size_t off_kofs   = 256;
    size_t off_bcnt   = 384;
    size_t off_pairs  = (off_bcnt + (size_t)KK * nblk * 4 + 15) & ~(size_t)15;
    size_t off_pos    = off_pairs + (size_t)KK * N * sizeof(int2);
    size_t off_part   = (off_pos + (size_t)KK * N * 4 + 15) & ~(size_t)15;

    long long cap_ll = ((long long)ws_size - (long long)off_part) / (COUT * 4);
    int cap = (cap_ll < 0) ? 0 : (cap_ll > (long long)KK * N ? (long long)KK * N : (int)cap_ll);

    if (ws_size >= off_part && nblk <= 256) {
        int*   counts = (int*)((char*)d_ws + off_counts);
        int*   tbase  = (int*)((char*)d_ws + off_tbase);
        int*   kofs   = (int*)((char*)d_ws + off_kofs);
        int*   bcnt   = (int*)((char*)d_ws + off_bcnt);
        int2*  pairs  = (int2*)((char*)d_ws + off_pairs);
        int*   pos    = (int*)((char*)d_ws + off_pos);
        float* part   = (float*)((char*)d_ws + off_part);

        dim3 g1(nblk, KK);
        count_valid<<<g1, 256, 0, stream>>>(nbr, N, nblk, bcnt);
        scan_blocks<<<KK, 256, 0, stream>>>(bcnt, nblk, counts);
        tile_bases<<<1, 64, 0, stream>>>(counts, tbase, kofs);
        scatter_pairs<<<g1, 256, 0, stream>>>(nbr, N, nblk, bcnt, kofs, pairs, pos);

        spconv_center<<<(N + TM - 1) / TM, 256, 0, stream>>>(feats, Wb, nbr, out, N);
        spconv_partial<<<512, 256, 0, stream>>>(feats, Wb, pairs, counts, tbase, kofs,
                                                part, out, N, cap);
        reduce_out<<<(N + 7) / 8, 256, 0, stream>>>(part, pos, out, N, cap);
    } else {
        naive_spconv<<<N, 128, 0, stream>>>(feats, Wb, nbr, out, N);
    }
}

// Round 4
// 60.076 us; speedup vs baseline: 5.7344x; 1.6371x over previous
//
#include <hip/hip_runtime.h>
#include <stddef.h>

#define CIN  128
#define COUT 128
#define KK   27
#define TM   64

typedef short bf16x8 __attribute__((ext_vector_type(8)));
typedef short bf16x4 __attribute__((ext_vector_type(4)));
typedef float f32x4  __attribute__((ext_vector_type(4)));

__device__ __forceinline__ short f2bf(float f) {
    unsigned u = __float_as_uint(f);
    unsigned r = (u + 0x7fffu + ((u >> 16) & 1u)) >> 16;
    return (short)r;
}
__device__ __forceinline__ float bf2f(short s) {
    unsigned u = ((unsigned)(unsigned short)s) << 16;
    return __uint_as_float(u);
}

// ============================================================================
// Prep 1: feats fp32 -> bf16. 8 elems/thread.
// ============================================================================
__global__ __launch_bounds__(256) void conv_bf16(
    const float* __restrict__ x, short* __restrict__ y, int total8)
{
    int i = blockIdx.x * 256 + threadIdx.x;
    if (i >= total8) return;
    const float4* p = reinterpret_cast<const float4*>(x) + (size_t)i * 2;
    float4 a = p[0], b = p[1];
    bf16x8 v = { f2bf(a.x), f2bf(a.y), f2bf(a.z), f2bf(a.w),
                 f2bf(b.x), f2bf(b.y), f2bf(b.z), f2bf(b.w) };
    reinterpret_cast<bf16x8*>(y)[i] = v;
}

// ============================================================================
// Prep 2: pack W fp32 [27][128][128] -> bf16 in MFMA B-fragment lane order.
// Wp[((k*4+ks)*8+nf)*512 + lane*8 + j] = bf16( W[k][ks*32+(lane>>4)*8+j][nf*16+(lane&15)] )
// ============================================================================
__global__ __launch_bounds__(256) void pack_W(
    const float* __restrict__ W, short* __restrict__ Wp)
{
    int fl = blockIdx.x * 256 + threadIdx.x;
    if (fl >= KK * 4 * 8 * 64) return;
    int lane = fl & 63, nf = (fl >> 6) & 7, ks = (fl >> 9) & 3, k = fl >> 11;
    int col  = nf * 16 + (lane & 15);
    int krow = ks * 32 + (lane >> 4) * 8;
    bf16x8 v;
    #pragma unroll
    for (int j = 0; j < 8; ++j)
        v[j] = f2bf(W[((size_t)k * CIN + krow + j) * COUT + col]);
    *reinterpret_cast<bf16x8*>(Wp + (size_t)fl * 8) = v;
}

// ============================================================================
// Compaction phase 1: count valid per (k, block) via ballot. No atomics.
// ============================================================================
__global__ __launch_bounds__(256) void count_valid(
    const int* __restrict__ nbr, int N, int nblk, int* __restrict__ blk_cnt)
{
    int k = blockIdx.y;
    int n = blockIdx.x * 256 + threadIdx.x;
    bool valid = (k != 13) && (n < N) && (nbr[(size_t)k * N + n] >= 0);
    unsigned long long m = __ballot(valid);
    __shared__ int wcnt[4];
    int wave = threadIdx.x >> 6;
    if ((threadIdx.x & 63) == 0) wcnt[wave] = __popcll(m);
    __syncthreads();
    if (threadIdx.x == 0)
        blk_cnt[(size_t)k * nblk + blockIdx.x] = wcnt[0] + wcnt[1] + wcnt[2] + wcnt[3];
}

// ============================================================================
// Compaction phase 2: per-k exclusive scan (nblk <= 256); totals -> counts.
// ============================================================================
__global__ __launch_bounds__(256) void scan_blocks(
    int* __restrict__ blk_cnt, int nblk, int* __restrict__ counts)
{
    int k = blockIdx.x;
    int tid = threadIdx.x;
    __shared__ int buf[256];
    int v = (tid < nblk) ? blk_cnt[(size_t)k * nblk + tid] : 0;
    buf[tid] = v;
    __syncthreads();
    for (int off = 1; off < 256; off <<= 1) {
        int t = (tid >= off) ? buf[tid - off] : 0;
        __syncthreads();
        buf[tid] += t;
        __syncthreads();
    }
    if (tid < nblk) blk_cnt[(size_t)k * nblk + tid] = buf[tid] - v;  // exclusive
    if (tid == 255) counts[k] = buf[255];
}

// ============================================================================
// Compaction phase 3: tbase (tile scan), kofs (entry scan).
// ============================================================================
__global__ void tile_bases(const int* __restrict__ counts,
                           int* __restrict__ tbase, int* __restrict__ kofs)
{
    if (threadIdx.x == 0) {
        int tacc = 0, eacc = 0;
        for (int k = 0; k < KK; ++k) {
            tbase[k] = tacc; tacc += (counts[k] + TM - 1) / TM;
            kofs[k]  = eacc; eacc += counts[k];
        }
        tbase[KK] = tacc;
        kofs[KK]  = eacc;
    }
}

// ============================================================================
// Compaction phase 4: scatter pairs at global entry offset kofs[k]+idx;
// pos[k*N+n] = that offset or -1.
// ============================================================================
__global__ __launch_bounds__(256) void scatter_pairs(
    const int* __restrict__ nbr, int N, int nblk,
    const int* __restrict__ blk_cnt, const int* __restrict__ kofs,
    int2* __restrict__ pairs, int* __restrict__ pos)
{
    int k = blockIdx.y;
    int n = blockIdx.x * 256 + threadIdx.x;
    int src = -1;
    if (k != 13 && n < N) src = nbr[(size_t)k * N + n];
    bool valid = (src >= 0);
    unsigned long long m = __ballot(valid);
    __shared__ int wcnt[4];
    int wave = threadIdx.x >> 6;
    int lane = threadIdx.x & 63;
    if (lane == 0) wcnt[wave] = __popcll(m);
    __syncthreads();
    if (n >= N) return;
    int base = blk_cnt[(size_t)k * nblk + blockIdx.x];
    for (int w = 0; w < wave; ++w) base += wcnt[w];
    int pfx = __popcll(m & ((1ull << lane) - 1ull));
    int g = kofs[k] + base + pfx;
    if (valid) pairs[g] = make_int2(n, src);
    pos[(size_t)k * N + n] = valid ? g : -1;
}

// ============================================================================
// Center GEMM, bf16 MFMA: out[n] = feats[nbr13[n]] @ W13. 64x128 tile, 4 waves.
// A: LDS [64][136] bf16 (pad 8 -> bank-uniform b128 reads).
// B: preloaded fragment-ordered from Wp (L2-hot, 16B/lane loads).
// ============================================================================
__global__ __launch_bounds__(256) void center_mfma(
    const short* __restrict__ featsb, const short* __restrict__ Wp13,
    const int* __restrict__ nbr13, float* __restrict__ out, int N)
{
    const int tile0 = blockIdx.x * TM;
    __shared__ short Asub[TM][136];

    #pragma unroll
    for (int j = 0; j < 4; ++j) {
        int slot = threadIdx.x + 256 * j;        // 0..1023
        int row = slot >> 4, cg = slot & 15;
        int r = tile0 + row;
        bf16x8 v = {0,0,0,0,0,0,0,0};
        if (r < N) {
            int src = nbr13[r];
            if (src >= 0)
                v = *reinterpret_cast<const bf16x8*>(featsb + (size_t)src * CIN + cg * 8);
        }
        *reinterpret_cast<bf16x8*>(&Asub[row][cg * 8]) = v;
    }

    const int wave = threadIdx.x >> 6, lane = threadIdx.x & 63;
    const int lrow = lane & 15, lhi = lane >> 4;

    bf16x8 b[2][4];
    #pragma unroll
    for (int nf = 0; nf < 2; ++nf)
        #pragma unroll
        for (int ks = 0; ks < 4; ++ks)
            b[nf][ks] = *reinterpret_cast<const bf16x8*>(
                Wp13 + ((size_t)(ks * 8 + wave * 2 + nf) * 64 + lane) * 8);

    __syncthreads();

    f32x4 zero = {0.f, 0.f, 0.f, 0.f};
    f32x4 acc[4][2];
    #pragma unroll
    for (int mf = 0; mf < 4; ++mf) { acc[mf][0] = zero; acc[mf][1] = zero; }

    #pragma unroll
    for (int ks = 0; ks < 4; ++ks)
        #pragma unroll
        for (int mf = 0; mf < 4; ++mf) {
            bf16x8 a = *reinterpret_cast<const bf16x8*>(
                &Asub[mf * 16 + lrow][ks * 32 + lhi * 8]);
            acc[mf][0] = __builtin_amdgcn_mfma_f32_16x16x32_bf16(a, b[0][ks], acc[mf][0], 0, 0, 0);
            acc[mf][1] = __builtin_amdgcn_mfma_f32_16x16x32_bf16(a, b[1][ks], acc[mf][1], 0, 0, 0);
        }

    #pragma unroll
    for (int mf = 0; mf < 4; ++mf)
        #pragma unroll
        for (int nf = 0; nf < 2; ++nf)
            #pragma unroll
            for (int j = 0; j < 4; ++j) {
                int r = tile0 + mf * 16 + lhi * 4 + j;
                if (r < N)
                    out[(size_t)r * COUT + wave * 32 + nf * 16 + lrow] = acc[mf][nf][j];
            }
}

// ============================================================================
// Sparse GEMM, bf16 MFMA: persistent blocks walk tile list; rows from pairs;
// results -> bf16 partial[goff] (collision-free); overflow -> atomicAdd out.
// ============================================================================
__global__ __launch_bounds__(256) void sparse_mfma(
    const short* __restrict__ featsb, const short* __restrict__ Wp,
    const int2* __restrict__ pairs, const int* __restrict__ counts,
    const int* __restrict__ tbase, const int* __restrict__ kofs,
    short* __restrict__ partial, float* __restrict__ out, int N, int cap)
{
    __shared__ short Asub[TM][136];
    __shared__ int n_of[TM];
    __shared__ int sk, stile0, scnt, skof;

    const int total = tbase[KK];
    const int wave = threadIdx.x >> 6, lane = threadIdx.x & 63;
    const int lrow = lane & 15, lhi = lane >> 4;

    for (int t = blockIdx.x; t < total; t += gridDim.x) {
        if (threadIdx.x == 0) {
            int k = 0;
            while (!(t >= tbase[k] && t < tbase[k + 1])) ++k;
            sk = k; stile0 = (t - tbase[k]) * TM; scnt = counts[k]; skof = kofs[k];
        }
        __syncthreads();
        const int k = sk, tile0 = stile0, cnt = scnt, kof = skof;

        bf16x8 b[2][4];
        #pragma unroll
        for (int nf = 0; nf < 2; ++nf)
            #pragma unroll
            for (int ks = 0; ks < 4; ++ks)
                b[nf][ks] = *reinterpret_cast<const bf16x8*>(
                    Wp + ((size_t)((k * 4 + ks) * 8 + wave * 2 + nf) * 64 + lane) * 8);

        #pragma unroll
        for (int j = 0; j < 4; ++j) {
            int slot = threadIdx.x + 256 * j;
            int row = slot >> 4, cg = slot & 15;
            int r = tile0 + row;
            bf16x8 v = {0,0,0,0,0,0,0,0};
            int n_out = -1;
            if (r < cnt) {
                int2 p = pairs[kof + r];
                n_out = p.x;
                v = *reinterpret_cast<const bf16x8*>(featsb + (size_t)p.y * CIN + cg * 8);
            }
            *reinterpret_cast<bf16x8*>(&Asub[row][cg * 8]) = v;
            if (cg == 0) n_of[row] = n_out;
        }
        __syncthreads();

        f32x4 zero = {0.f, 0.f, 0.f, 0.f};
        f32x4 acc[4][2];
        #pragma unroll
        for (int mf = 0; mf < 4; ++mf) { acc[mf][0] = zero; acc[mf][1] = zero; }

        #pragma unroll
        for (int ks = 0; ks < 4; ++ks)
            #pragma unroll
            for (int mf = 0; mf < 4; ++mf) {
                bf16x8 a = *reinterpret_cast<const bf16x8*>(
                    &Asub[mf * 16 + lrow][ks * 32 + lhi * 8]);
                acc[mf][0] = __builtin_amdgcn_mfma_f32_16x16x32_bf16(a, b[0][ks], acc[mf][0], 0, 0, 0);
                acc[mf][1] = __builtin_amdgcn_mfma_f32_16x16x32_bf16(a, b[1][ks], acc[mf][1], 0, 0, 0);
            }

        #pragma unroll
        for (int mf = 0; mf < 4; ++mf)
            #pragma unroll
            for (int j = 0; j < 4; ++j) {
                int rr = mf * 16 + lhi * 4 + j;
                int gr = tile0 + rr;
                if (gr >= cnt) continue;
                int goff = kof + gr;
                int col = wave * 32 + lrow;
                if (goff < cap) {
                    short* dst = partial + (size_t)goff * COUT + col;
                    dst[0]  = f2bf(acc[mf][0][j]);
                    dst[16] = f2bf(acc[mf][1][j]);
                } else {
                    float* dst = out + (size_t)n_of[rr] * COUT + col;
                    atomicAdd(dst,      acc[mf][0][j]);
                    atomicAdd(dst + 16, acc[mf][1][j]);
                }
            }
        __syncthreads();   // protect Asub/n_of before next tile
    }
}

// ============================================================================
// Reduce: out[n] += sum_k bf16 partial[pos[k,n]]. 8 rows/block, 32 lanes/row.
// Single owner per n -> plain RMW, deterministic k-order.
// ============================================================================
__global__ __launch_bounds__(256) void reduce_out(
    const short* __restrict__ partial, const int* __restrict__ pos,
    float* __restrict__ out, int N, int cap)
{
    int n0 = blockIdx.x * 8;
    __shared__ int pos_s[8][28];
    int i = threadIdx.x;
    if (i < 8 * KK) {
        int k = i / 8, r = i % 8;
        int n = n0 + r;
        pos_s[r][k] = (n < N) ? pos[(size_t)k * N + n] : -1;
    }
    __syncthreads();

    int row  = threadIdx.x >> 5;
    int lane = threadIdx.x & 31;
    int n = n0 + row;
    if (n >= N) return;

    float acc0 = 0.f, acc1 = 0.f, acc2 = 0.f, acc3 = 0.f;
    bool any = false;
    #pragma unroll
    for (int k = 0; k < KK; ++k) {
        int g = pos_s[row][k];
        if (g >= 0 && g < cap) {
            any = true;
            bf16x4 v = *reinterpret_cast<const bf16x4*>(partial + (size_t)g * COUT + lane * 4);
            acc0 += bf2f(v[0]); acc1 += bf2f(v[1]); acc2 += bf2f(v[2]); acc3 += bf2f(v[3]);
        }
    }
    if (any) {
        float4* dst = reinterpret_cast<float4*>(out + (size_t)n * COUT + lane * 4);
        float4 o = *dst;
        o.x += acc0; o.y += acc1; o.z += acc2; o.w += acc3;
        *dst = o;
    }
}

// ============================================================================
// Fallback (ws too small): one block per voxel, fp32.
// ============================================================================
__global__ __launch_bounds__(128) void naive_spconv(
    const float* __restrict__ feats, const float* __restrict__ Wbase,
    const int* __restrict__ nbr, float* __restrict__ out, int N)
{
    int n  = blockIdx.x;
    int co = threadIdx.x;
    __shared__ float frow[CIN];
    float acc = 0.f;
    for (int k = 0; k < KK; ++k) {
        int src = nbr[(size_t)k * N + n];
        if (src < 0) continue;
        __syncthreads();
        frow[co] = feats[(size_t)src * CIN + co];
        __syncthreads();
        const float* Wk = Wbase + (size_t)k * CIN * COUT;
        #pragma unroll 8
        for (int ci = 0; ci < CIN; ++ci)
            acc = fmaf(frow[ci], Wk[ci * COUT + co], acc);
    }
    out[(size_t)n * COUT + co] = acc;
}

extern "C" void kernel_launch(void* const* d_in, const int* in_sizes, int n_in,
                              void* d_out, int out_size, void* d_ws, size_t ws_size,
                              hipStream_t stream) {
    const float* feats = (const float*)d_in[0];
    const float* Wb    = (const float*)d_in[1];
    const int*   nbr   = (const int*)d_in[2];
    float* out = (float*)d_out;
    const int N = in_sizes[0] / CIN;
    const int nblk = (N + 255) / 256;

    // ws layout: counts[32] | tbase[32] | kofs[32] | bcnt[27*nblk]
    //   | featsb bf16 N*128 | Wpack bf16 27*16384 | pairs int2 27N | pos int 27N
    //   | partial bf16 cap*128
    size_t off_counts = 0;
    size_t off_tbase  = 128;
    size_t off_kofs   = 256;
    size_t off_bcnt   = 384;
    size_t off_featsb = (off_bcnt + (size_t)KK * nblk * 4 + 255) & ~(size_t)255;
    size_t off_wpack  = (off_featsb + (size_t)N * CIN * 2 + 255) & ~(size_t)255;
    size_t off_pairs  = (off_wpack + (size_t)KK * 4 * 8 * 64 * 8 * 2 + 255) & ~(size_t)255;
    size_t off_pos    = off_pairs + (size_t)KK * N * sizeof(int2);
    size_t off_part   = (off_pos + (size_t)KK * N * 4 + 255) & ~(size_t)255;

    long long cap_ll = ((long long)ws_size - (long long)off_part) / (COUT * 2);
    long long maxent = (long long)KK * N;
    int cap = (cap_ll < 0) ? 0 : (cap_ll > maxent ? (int)maxent : (int)cap_ll);

    if (ws_size >= off_part && nblk <= 256) {
        int*   counts = (int*)((char*)d_ws + off_counts);
        int*   tbase  = (int*)((char*)d_ws + off_tbase);
        int*   kofs   = (int*)((char*)d_ws + off_kofs);
        int*   bcnt   = (int*)((char*)d_ws + off_bcnt);
        short* featsb = (short*)((char*)d_ws + off_featsb);
        short* wpack  = (short*)((char*)d_ws + off_wpack);
        int2*  pairs  = (int2*)((char*)d_ws + off_pairs);
        int*   pos    = (int*)((char*)d_ws + off_pos);
        short* part   = (short*)((char*)d_ws + off_part);

        int total8 = N * CIN / 8;
        conv_bf16<<<(total8 + 255) / 256, 256, 0, stream>>>(feats, featsb, total8);
        pack_W<<<(KK * 4 * 8 * 64 + 255) / 256, 256, 0, stream>>>(Wb, wpack);

        dim3 g1(nblk, KK);
        count_valid<<<g1, 256, 0, stream>>>(nbr, N, nblk, bcnt);
        scan_blocks<<<KK, 256, 0, stream>>>(bcnt, nblk, counts);
        tile_bases<<<1, 64, 0, stream>>>(counts, tbase, kofs);
        scatter_pairs<<<g1, 256, 0, stream>>>(nbr, N, nblk, bcnt, kofs, pairs, pos);

        center_mfma<<<(N + TM - 1) / TM, 256, 0, stream>>>(
            featsb, wpack + (size_t)13 * 4 * 8 * 64 * 8, nbr + (size_t)13 * N, out, N);
        sparse_mfma<<<512, 256, 0, stream>>>(featsb, wpack, pairs, counts, tbase, kofs,
                                             part, out, N, cap);
        reduce_out<<<(N + 7) / 8, 256, 0, stream>>>(part, pos, out, N, cap);
    } else {
        naive_spconv<<<N, 128, 0, stream>>>(feats, Wb, nbr, out, N);
    }
}

// Round 5
// 52.391 us; speedup vs baseline: 6.5756x; 1.1467x over previous
//
#include <hip/hip_runtime.h>
#include <stddef.h>

#define CIN  128
#define COUT 128
#define KK   27
#define TM   64
#define SB   512   // persistent sparse blocks

typedef short bf16x8 __attribute__((ext_vector_type(8)));
typedef short bf16x4 __attribute__((ext_vector_type(4)));
typedef float f32x4  __attribute__((ext_vector_type(4)));

__device__ __forceinline__ short f2bf(float f) {
    unsigned u = __float_as_uint(f);
    unsigned r = (u + 0x7fffu + ((u >> 16) & 1u)) >> 16;
    return (short)r;
}
__device__ __forceinline__ float bf2f(short s) {
    unsigned u = ((unsigned)(unsigned short)s) << 16;
    return __uint_as_float(u);
}

#define PACK_UNITS (KK * 4 * 8 * 64)            // 55296 fragment-slots
#define PACKB ((PACK_UNITS + 255) / 256)        // 216 blocks

// ============================================================================
// Prep (fused): blocks [0, PACKB) pack W into MFMA B-fragment lane order;
// blocks [PACKB, ...) count valid entries per (k, 256-chunk) via ballot.
// Wp[((k*4+ks)*8+nf)*512 + lane*8 + j] =
//     bf16( W[k][ks*32+(lane>>4)*8+j][nf*16+(lane&15)] )
// ============================================================================
__global__ __launch_bounds__(256) void prep(
    const float* __restrict__ W, short* __restrict__ Wp,
    const int* __restrict__ nbr, int N, int nblk, int* __restrict__ blk_cnt)
{
    int b = blockIdx.x;
    if (b < PACKB) {
        int fl = b * 256 + threadIdx.x;
        if (fl >= PACK_UNITS) return;
        int lane = fl & 63, nf = (fl >> 6) & 7, ks = (fl >> 9) & 3, k = fl >> 11;
        int col  = nf * 16 + (lane & 15);
        int krow = ks * 32 + (lane >> 4) * 8;
        bf16x8 v;
        #pragma unroll
        for (int j = 0; j < 8; ++j)
            v[j] = f2bf(W[((size_t)k * CIN + krow + j) * COUT + col]);
        *reinterpret_cast<bf16x8*>(Wp + (size_t)fl * 8) = v;
    } else {
        int bb = b - PACKB;
        int k = bb / nblk, blk = bb - k * nblk;
        int n = blk * 256 + threadIdx.x;
        bool valid = (k != 13) && (n < N) && (nbr[(size_t)k * N + n] >= 0);
        unsigned long long m = __ballot(valid);
        __shared__ int wcnt[4];
        int wave = threadIdx.x >> 6;
        if ((threadIdx.x & 63) == 0) wcnt[wave] = __popcll(m);
        __syncthreads();
        if (threadIdx.x == 0)
            blk_cnt[(size_t)k * nblk + blk] = wcnt[0] + wcnt[1] + wcnt[2] + wcnt[3];
    }
}

// ============================================================================
// Per-k exclusive scan of block counts (nblk <= 256); totals -> counts[k].
// ============================================================================
__global__ __launch_bounds__(256) void scan_blocks(
    int* __restrict__ blk_cnt, int nblk, int* __restrict__ counts)
{
    int k = blockIdx.x;
    int tid = threadIdx.x;
    __shared__ int buf[256];
    int v = (tid < nblk) ? blk_cnt[(size_t)k * nblk + tid] : 0;
    buf[tid] = v;
    __syncthreads();
    for (int off = 1; off < 256; off <<= 1) {
        int t = (tid >= off) ? buf[tid - off] : 0;
        __syncthreads();
        buf[tid] += t;
        __syncthreads();
    }
    if (tid < nblk) blk_cnt[(size_t)k * nblk + tid] = buf[tid] - v;  // exclusive
    if (tid == 255) counts[k] = buf[255];
}

// ============================================================================
// Scatter pairs at global entry offset kofs[k]+idx (kofs computed inline);
// pos[k*N+n] = that offset or -1. No atomics.
// ============================================================================
__global__ __launch_bounds__(256) void scatter_pairs(
    const int* __restrict__ nbr, int N, int nblk,
    const int* __restrict__ blk_cnt, const int* __restrict__ counts,
    int2* __restrict__ pairs, int* __restrict__ pos)
{
    int k = blockIdx.y;
    __shared__ int skof, wcnt[4];
    if (threadIdx.x == 0) {
        int a = 0;
        for (int i = 0; i < k; ++i) a += counts[i];
        skof = a;
    }
    int n = blockIdx.x * 256 + threadIdx.x;
    int src = -1;
    if (k != 13 && n < N) src = nbr[(size_t)k * N + n];
    bool valid = (src >= 0);
    unsigned long long m = __ballot(valid);
    int wave = threadIdx.x >> 6;
    int lane = threadIdx.x & 63;
    if (lane == 0) wcnt[wave] = __popcll(m);
    __syncthreads();
    if (n >= N) return;
    int base = blk_cnt[(size_t)k * nblk + blockIdx.x];
    for (int w = 0; w < wave; ++w) base += wcnt[w];
    int pfx = __popcll(m & ((1ull << lane) - 1ull));
    int g = skof + base + pfx;
    if (valid) pairs[g] = make_int2(n, src);
    pos[(size_t)k * N + n] = valid ? g : -1;
}

// ============================================================================
// Unified GEMM: blocks < ctiles do the dense center tile (k=13, write out);
// remaining SB blocks walk the sparse tile list (write bf16 partial).
// A-tile: LDS [64][128] bf16 with 16B-chunk XOR swizzle (cg ^= row&7) ->
// bank-spread ds_read_b128. In-register fp32->bf16 conversion during staging.
// B-frags: fragment-ordered Wp, 16B/lane L2-hot loads.
// ============================================================================
__global__ __launch_bounds__(256) void gemm_all(
    const float* __restrict__ feats, const short* __restrict__ Wp,
    const int* __restrict__ nbr, const int2* __restrict__ pairs,
    const int* __restrict__ counts,
    short* __restrict__ partial, float* __restrict__ out,
    int N, int cap, int ctiles)
{
    __shared__ short Asub[TM * 128];
    __shared__ int n_of[TM];
    __shared__ int tb[KK + 1], ko[KK + 1];
    __shared__ int sk, stile0, scnt, skof;

    const int wave = threadIdx.x >> 6, lane = threadIdx.x & 63;
    const int lrow = lane & 15, lhi = lane >> 4;

    if (blockIdx.x < ctiles) {
        // ------------------------- center tile -------------------------
        const int tile0 = blockIdx.x * TM;
        const int* nbr13 = nbr + (size_t)13 * N;
        const short* Wp13 = Wp + (size_t)13 * 16384;

        #pragma unroll
        for (int j = 0; j < 4; ++j) {
            int slot = threadIdx.x + 256 * j;      // 64 rows x 16 chunks
            int row = slot >> 4, cg = slot & 15;
            int r = tile0 + row;
            bf16x8 v = {0,0,0,0,0,0,0,0};
            if (r < N) {
                int src = nbr13[r];
                if (src >= 0) {
                    const float4* p = reinterpret_cast<const float4*>(
                        feats + (size_t)src * CIN + cg * 8);
                    float4 a = p[0], b2 = p[1];
                    v = bf16x8{ f2bf(a.x), f2bf(a.y), f2bf(a.z), f2bf(a.w),
                                f2bf(b2.x), f2bf(b2.y), f2bf(b2.z), f2bf(b2.w) };
                }
            }
            int sw = cg ^ (row & 7);
            *reinterpret_cast<bf16x8*>(&Asub[row * 128 + sw * 8]) = v;
        }

        bf16x8 b[2][4];
        #pragma unroll
        for (int nf = 0; nf < 2; ++nf)
            #pragma unroll
            for (int ks = 0; ks < 4; ++ks)
                b[nf][ks] = *reinterpret_cast<const bf16x8*>(
                    Wp13 + ((size_t)(ks * 8 + wave * 2 + nf) * 64 + lane) * 8);

        __syncthreads();

        f32x4 zero = {0.f, 0.f, 0.f, 0.f};
        f32x4 acc[4][2];
        #pragma unroll
        for (int mf = 0; mf < 4; ++mf) { acc[mf][0] = zero; acc[mf][1] = zero; }

        #pragma unroll
        for (int ks = 0; ks < 4; ++ks)
            #pragma unroll
            for (int mf = 0; mf < 4; ++mf) {
                int row = mf * 16 + lrow;
                int sw = (ks * 4 + lhi) ^ (lrow & 7);
                bf16x8 a = *reinterpret_cast<const bf16x8*>(&Asub[row * 128 + sw * 8]);
                acc[mf][0] = __builtin_amdgcn_mfma_f32_16x16x32_bf16(a, b[0][ks], acc[mf][0], 0, 0, 0);
                acc[mf][1] = __builtin_amdgcn_mfma_f32_16x16x32_bf16(a, b[1][ks], acc[mf][1], 0, 0, 0);
            }

        #pragma unroll
        for (int mf = 0; mf < 4; ++mf)
            #pragma unroll
            for (int nf = 0; nf < 2; ++nf)
                #pragma unroll
                for (int j = 0; j < 4; ++j) {
                    int r = tile0 + mf * 16 + lhi * 4 + j;
                    if (r < N)
                        out[(size_t)r * COUT + wave * 32 + nf * 16 + lrow] = acc[mf][nf][j];
                }
        return;
    }

    // --------------------------- sparse tiles ---------------------------
    if (threadIdx.x == 0) {
        int ta = 0, ea = 0;
        for (int k = 0; k < KK; ++k) {
            tb[k] = ta; ta += (counts[k] + TM - 1) / TM;
            ko[k] = ea; ea += counts[k];
        }
        tb[KK] = ta; ko[KK] = ea;
    }
    __syncthreads();
    const int total = tb[KK];

    for (int t = blockIdx.x - ctiles; t < total; t += SB) {
        if (threadIdx.x == 0) {
            int k = 0;
            while (!(t >= tb[k] && t < tb[k + 1])) ++k;
            sk = k; stile0 = (t - tb[k]) * TM; scnt = counts[k]; skof = ko[k];
        }
        __syncthreads();
        const int k = sk, tile0 = stile0, cnt = scnt, kof = skof;

        bf16x8 b[2][4];
        #pragma unroll
        for (int nf = 0; nf < 2; ++nf)
            #pragma unroll
            for (int ks = 0; ks < 4; ++ks)
                b[nf][ks] = *reinterpret_cast<const bf16x8*>(
                    Wp + ((size_t)((k * 4 + ks) * 8 + wave * 2 + nf) * 64 + lane) * 8);

        #pragma unroll
        for (int j = 0; j < 4; ++j) {
            int slot = threadIdx.x + 256 * j;
            int row = slot >> 4, cg = slot & 15;
            int r = tile0 + row;
            bf16x8 v = {0,0,0,0,0,0,0,0};
            int n_out = -1;
            if (r < cnt) {
                int2 p = pairs[kof + r];
                n_out = p.x;
                const float4* q = reinterpret_cast<const float4*>(
                    feats + (size_t)p.y * CIN + cg * 8);
                float4 a = q[0], b2 = q[1];
                v = bf16x8{ f2bf(a.x), f2bf(a.y), f2bf(a.z), f2bf(a.w),
                            f2bf(b2.x), f2bf(b2.y), f2bf(b2.z), f2bf(b2.w) };
            }
            int sw = cg ^ (row & 7);
            *reinterpret_cast<bf16x8*>(&Asub[row * 128 + sw * 8]) = v;
            if (cg == 0) n_of[row] = n_out;
        }
        __syncthreads();

        f32x4 zero = {0.f, 0.f, 0.f, 0.f};
        f32x4 acc[4][2];
        #pragma unroll
        for (int mf = 0; mf < 4; ++mf) { acc[mf][0] = zero; acc[mf][1] = zero; }

        #pragma unroll
        for (int ks = 0; ks < 4; ++ks)
            #pragma unroll
            for (int mf = 0; mf < 4; ++mf) {
                int row = mf * 16 + lrow;
                int sw = (ks * 4 + lhi) ^ (lrow & 7);
                bf16x8 a = *reinterpret_cast<const bf16x8*>(&Asub[row * 128 + sw * 8]);
                acc[mf][0] = __builtin_amdgcn_mfma_f32_16x16x32_bf16(a, b[0][ks], acc[mf][0], 0, 0, 0);
                acc[mf][1] = __builtin_amdgcn_mfma_f32_16x16x32_bf16(a, b[1][ks], acc[mf][1], 0, 0, 0);
            }

        #pragma unroll
        for (int mf = 0; mf < 4; ++mf)
            #pragma unroll
            for (int j = 0; j < 4; ++j) {
                int rr = mf * 16 + lhi * 4 + j;
                int gr = tile0 + rr;
                if (gr >= cnt) continue;
                int goff = kof + gr;
                int col = wave * 32 + lrow;
                if (goff < cap) {
                    short* dst = partial + (size_t)goff * COUT + col;
                    dst[0]  = f2bf(acc[mf][0][j]);
                    dst[16] = f2bf(acc[mf][1][j]);
                } else {
                    float* dst = out + (size_t)n_of[rr] * COUT + col;
                    atomicAdd(dst,      acc[mf][0][j]);
                    atomicAdd(dst + 16, acc[mf][1][j]);
                }
            }
        __syncthreads();   // protect Asub/n_of before next tile
    }
}

// ============================================================================
// Reduce: out[n] += sum_k bf16 partial[pos[k,n]]. 8 rows/block, 32 lanes/row.
// Single owner per n -> plain RMW, deterministic k-order.
// ============================================================================
__global__ __launch_bounds__(256) void reduce_out(
    const short* __restrict__ partial, const int* __restrict__ pos,
    float* __restrict__ out, int N, int cap)
{
    int n0 = blockIdx.x * 8;
    __shared__ int pos_s[8][28];
    int i = threadIdx.x;
    if (i < 8 * KK) {
        int k = i / 8, r = i % 8;
        int n = n0 + r;
        pos_s[r][k] = (n < N) ? pos[(size_t)k * N + n] : -1;
    }
    __syncthreads();

    int row  = threadIdx.x >> 5;
    int lane = threadIdx.x & 31;
    int n = n0 + row;
    if (n >= N) return;

    float acc0 = 0.f, acc1 = 0.f, acc2 = 0.f, acc3 = 0.f;
    bool any = false;
    #pragma unroll
    for (int k = 0; k < KK; ++k) {
        int g = pos_s[row][k];
        if (g >= 0 && g < cap) {
            any = true;
            bf16x4 v = *reinterpret_cast<const bf16x4*>(partial + (size_t)g * COUT + lane * 4);
            acc0 += bf2f(v[0]); acc1 += bf2f(v[1]); acc2 += bf2f(v[2]); acc3 += bf2f(v[3]);
        }
    }
    if (any) {
        float4* dst = reinterpret_cast<float4*>(out + (size_t)n * COUT + lane * 4);
        float4 o = *dst;
        o.x += acc0; o.y += acc1; o.z += acc2; o.w += acc3;
        *dst = o;
    }
}

// ============================================================================
// Fallback (ws too small): one block per voxel, fp32.
// ============================================================================
__global__ __launch_bounds__(128) void naive_spconv(
    const float* __restrict__ feats, const float* __restrict__ Wbase,
    const int* __restrict__ nbr, float* __restrict__ out, int N)
{
    int n  = blockIdx.x;
    int co = threadIdx.x;
    __shared__ float frow[CIN];
    float acc = 0.f;
    for (int k = 0; k < KK; ++k) {
        int src = nbr[(size_t)k * N + n];
        if (src < 0) continue;
        __syncthreads();
        frow[co] = feats[(size_t)src * CIN + co];
        __syncthreads();
        const float* Wk = Wbase + (size_t)k * CIN * COUT;
        #pragma unroll 8
        for (int ci = 0; ci < CIN; ++ci)
            acc = fmaf(frow[ci], Wk[ci * COUT + co], acc);
    }
    out[(size_t)n * COUT + co] = acc;
}

extern "C" void kernel_launch(void* const* d_in, const int* in_sizes, int n_in,
                              void* d_out, int out_size, void* d_ws, size_t ws_size,
                              hipStream_t stream) {
    const float* feats = (const float*)d_in[0];
    const float* Wb    = (const float*)d_in[1];
    const int*   nbr   = (const int*)d_in[2];
    float* out = (float*)d_out;
    const int N = in_sizes[0] / CIN;
    const int nblk = (N + 255) / 256;

    // ws layout: counts[32] | bcnt[27*nblk] | Wpack bf16 27*16384
    //            | pairs int2 27N | pos int 27N | partial bf16 cap*128
    size_t off_counts = 0;
    size_t off_bcnt   = 128;
    size_t off_wpack  = (off_bcnt + (size_t)KK * nblk * 4 + 255) & ~(size_t)255;
    size_t off_pairs  = (off_wpack + (size_t)KK * 16384 * 2 + 255) & ~(size_t)255;
    size_t off_pos    = off_pairs + (size_t)KK * N * sizeof(int2);
    size_t off_part   = (off_pos + (size_t)KK * N * 4 + 255) & ~(size_t)255;

    long long cap_ll = ((long long)ws_size - (long long)off_part) / (COUT * 2);
    long long maxent = (long long)KK * N;
    int cap = (cap_ll < 0) ? 0 : (cap_ll > maxent ? (int)maxent : (int)cap_ll);

    if (ws_size >= off_part && nblk <= 256) {
        int*   counts = (int*)((char*)d_ws + off_counts);
        int*   bcnt   = (int*)((char*)d_ws + off_bcnt);
        short* wpack  = (short*)((char*)d_ws + off_wpack);
        int2*  pairs  = (int2*)((char*)d_ws + off_pairs);
        int*   pos    = (int*)((char*)d_ws + off_pos);
        short* part   = (short*)((char*)d_ws + off_part);

        prep<<<PACKB + KK * nblk, 256, 0, stream>>>(Wb, wpack, nbr, N, nblk, bcnt);
        scan_blocks<<<KK, 256, 0, stream>>>(bcnt, nblk, counts);
        scatter_pairs<<<dim3(nblk, KK), 256, 0, stream>>>(nbr, N, nblk, bcnt, counts, pairs, pos);

        int ctiles = (N + TM - 1) / TM;
        gemm_all<<<ctiles + SB, 256, 0, stream>>>(feats, wpack, nbr, pairs, counts,
                                                  part, out, N, cap, ctiles);
        reduce_out<<<(N + 7) / 8, 256, 0, stream>>>(part, pos, out, N, cap);
    } else {
        naive_spconv<<<N, 128, 0, stream>>>(feats, Wb, nbr, out, N);
    }
}